// Round 7
// baseline (17.847 us; speedup 1.0000x reference)
//
#include <hip/hip_runtime.h>
#include <hip/hip_bf16.h>

// AngleTensor: out[b,i,j,k] = mask * arccos( (p_j - p_i) . (p_k - p_i) / (d_ij * d_ik) )
// mask = 0 when i==j || i==k || j==k; mag < 1e-10 -> mag = 1.
// positions: (B,N,3) f32, dist: (B,N,N) f32, out: (B,N,N,N) f32.
//
// cos = u_j . u_k with u_t = (p_t - p_i) * rcp(max(d_it, 1e-7)), staged in LDS.
// j==k (i!=j): c = |u_j|^2 -> clamp -> acos ~ 0 (mask arithmetic).
// i==j / i==k: forced c=1 via hoisted select -> acos = 0 exactly.
// Round 7: compile-time N=128, batched 4-row groups (prefetch 12 ds_reads ->
// compute 16 results -> burst 4 float4 stores). Math identical to round 6.

#define PI_F 3.14159265358979323846f

typedef float f32x2 __attribute__((ext_vector_type(2)));
typedef float f32x4 __attribute__((ext_vector_type(4)));

__device__ __forceinline__ f32x2 pk_fma(f32x2 a, f32x2 b, f32x2 c) {
    return __builtin_elementwise_fma(a, b, c);
}

// Quadratic minimax for acos(x)/sqrt(1-x) on [0,1]; endpoints exact. c==1 -> exact 0.
#define A0C 1.5707963f
#define A1C (-0.2025900f)
#define A2C 0.0460080f

__device__ __forceinline__ f32x2 acos2(f32x2 c) {
    f32x2 ax;
    ax.x = fabsf(c.x);
    ax.y = fabsf(c.y);
    const f32x2 a2 = {A2C, A2C}, a1 = {A1C, A1C}, a0 = {A0C, A0C};
    f32x2 p = pk_fma(ax, pk_fma(ax, a2, a1), a0);
    const f32x2 negone = {-1.0f, -1.0f}, one = {1.0f, 1.0f}, pi2 = {PI_F, PI_F};
    f32x2 om = pk_fma(ax, negone, one);          // 1 - ax  (>= 0)
    f32x2 s;
    s.x = __builtin_amdgcn_sqrtf(om.x);
    s.y = __builtin_amdgcn_sqrtf(om.y);
    f32x2 r = s * p;                             // v_pk_mul_f32
    f32x2 pir = pk_fma(r, negone, pi2);          // pi - r
    f32x2 out;
    out.x = (c.x < 0.0f) ? pir.x : r.x;
    out.y = (c.y < 0.0f) ? pir.y : r.y;
    return out;
}

__device__ __forceinline__ float prep(float craw, bool valid) {
    float c = __builtin_amdgcn_fmed3f(craw, -1.0f, 1.0f);
    return valid ? c : 1.0f;                     // masked -> acos gives exact 0
}

// Compile-time-N kernel (instantiated for N=128). Block = 256 threads, one (b,i)
// per (blockIdx.x, blockIdx.y), SPLIT=2 over blockIdx.z.
// Quarter jj = tid>>5 owns rows j = jj + 8*s + 16*m (m = 0..7); lane kq = tid&31
// owns k = 4*kq..4*kq+3, unit vectors pinned in registers.
template <int N>
__global__ __launch_bounds__(256) void angle_unit_t(const float* __restrict__ pos,
                                                    const float* __restrict__ dist,
                                                    float* __restrict__ out) {
    __shared__ float sux[N], suy[N], suz[N];

    const int i = blockIdx.x;
    const int b = blockIdx.y;
    const int s = blockIdx.z;

    const float* pb   = pos  + (size_t)b * N * 3;
    const float* drow = dist + ((size_t)b * N + i) * N;

    const float pix = pb[3 * i + 0];
    const float piy = pb[3 * i + 1];
    const float piz = pb[3 * i + 2];

    // Staging with all 256 threads: lo half writes u.x/u.y, hi half writes u.z.
    {
        const int t  = threadIdx.x & (N - 1);
        const bool hi = (int)threadIdx.x >= N;
        const float r = __builtin_amdgcn_rcpf(fmaxf(drow[t], 1e-7f));
        if (!hi) {
            sux[t] = (pb[3 * t + 0] - pix) * r;   // t == i: diff = 0 -> u = 0 (masked)
            suy[t] = (pb[3 * t + 1] - piy) * r;
        } else {
            suz[t] = (pb[3 * t + 2] - piz) * r;
        }
    }
    __syncthreads();

    const int kq = threadIdx.x & 31;
    const int jj = threadIdx.x >> 5;
    const int k0 = kq * 4;

    // k unit vectors pinned in registers as pairs (01, 23).
    const f32x4 vx = *reinterpret_cast<const f32x4*>(&sux[k0]);
    const f32x4 vy = *reinterpret_cast<const f32x4*>(&suy[k0]);
    const f32x4 vz = *reinterpret_cast<const f32x4*>(&suz[k0]);
    const f32x2 kx01 = {vx.x, vx.y}, kx23 = {vx.z, vx.w};
    const f32x2 ky01 = {vy.x, vy.y}, ky23 = {vy.z, vy.w};
    const f32x2 kz01 = {vz.x, vz.y}, kz23 = {vz.z, vz.w};

    // (k != i): j-invariant, hoisted.
    const bool ki0 = (k0 + 0) != i;
    const bool ki1 = (k0 + 1) != i;
    const bool ki2 = (k0 + 2) != i;
    const bool ki3 = (k0 + 3) != i;

    float* obase = out + ((size_t)b * N + i) * (size_t)(N * N);
    const int jbase = jj + 8 * s;                 // s in {0,1}: jbase in [0,16)

#pragma unroll
    for (int g = 0; g < 2; ++g) {
        // ---- phase 1: prefetch 4 rows' broadcast operands (12 ds_reads, one wait)
        int   jr[4];
        float ujx[4], ujy[4], ujz[4];
#pragma unroll
        for (int u = 0; u < 4; ++u) {
            jr[u]  = jbase + 16 * (4 * g + u);    // < N for N=128
            ujx[u] = sux[jr[u]];
            ujy[u] = suy[jr[u]];
            ujz[u] = suz[jr[u]];
        }
        // ---- phase 2: compute 16 results into registers
        f32x4 res[4];
#pragma unroll
        for (int u = 0; u < 4; ++u) {
            const bool jne = (jr[u] != i);
            const f32x2 jx = {ujx[u], ujx[u]}, jy = {ujy[u], ujy[u]}, jz = {ujz[u], ujz[u]};
            f32x2 c01 = pk_fma(jx, kx01, pk_fma(jy, ky01, jz * kz01));
            f32x2 c23 = pk_fma(jx, kx23, pk_fma(jy, ky23, jz * kz23));
            c01.x = prep(c01.x, jne && ki0);
            c01.y = prep(c01.y, jne && ki1);
            c23.x = prep(c23.x, jne && ki2);
            c23.y = prep(c23.y, jne && ki3);
            const f32x2 a01 = acos2(c01);
            const f32x2 a23 = acos2(c23);
            res[u].x = a01.x; res[u].y = a01.y; res[u].z = a23.x; res[u].w = a23.y;
        }
        // ---- phase 3: burst 4 back-to-back float4 stores
#pragma unroll
        for (int u = 0; u < 4; ++u) {
            *reinterpret_cast<f32x4*>(obase + (size_t)jr[u] * N + k0) = res[u];
        }
    }
}

// Generic scalar fallback (any N), grid-stride over all B*N^3 elements.
__global__ void angle_scalar(const float* __restrict__ pos,
                             const float* __restrict__ dist,
                             float* __restrict__ out, int N, long long total) {
    const long long NN  = (long long)N * N;
    const long long NNN = NN * N;
    for (long long idx = (long long)blockIdx.x * blockDim.x + threadIdx.x;
         idx < total; idx += (long long)gridDim.x * blockDim.x) {
        int k = (int)(idx % N);
        int j = (int)((idx / N) % N);
        int i = (int)((idx / NN) % N);
        int b = (int)(idx / NNN);

        const float* pb   = pos  + (size_t)b * N * 3;
        const float* drow = dist + ((size_t)b * N + i) * N;

        float pix = pb[i * 3 + 0], piy = pb[i * 3 + 1], piz = pb[i * 3 + 2];
        float rj = __builtin_amdgcn_rcpf(fmaxf(drow[j], 1e-7f));
        float rk = __builtin_amdgcn_rcpf(fmaxf(drow[k], 1e-7f));
        float ujx = (pb[j * 3 + 0] - pix) * rj, ujy = (pb[j * 3 + 1] - piy) * rj,
              ujz = (pb[j * 3 + 2] - piz) * rj;
        float ukx = (pb[k * 3 + 0] - pix) * rk, uky = (pb[k * 3 + 1] - piy) * rk,
              ukz = (pb[k * 3 + 2] - piz) * rk;
        bool valid = (i != j) && (i != k);
        float craw = fmaf(ujx, ukx, fmaf(ujy, uky, ujz * ukz));
        float c = prep(craw, valid);
        f32x2 cp = {c, c};
        out[idx] = acos2(cp).x;
    }
}

extern "C" void kernel_launch(void* const* d_in, const int* in_sizes, int n_in,
                              void* d_out, int out_size, void* d_ws, size_t ws_size,
                              hipStream_t stream) {
    const float* pos  = (const float*)d_in[0];
    const float* dist = (const float*)d_in[1];
    float* out = (float*)d_out;

    const long long pos_sz  = in_sizes[0];  // B*N*3
    const long long dist_sz = in_sizes[1];  // B*N*N
    const int N = (int)((3LL * dist_sz) / pos_sz);
    const int B = (int)(pos_sz / (3LL * (long long)N));

    if (N == 128) {
        dim3 grid(128, B, 2);                  // 2048 blocks for B=8
        angle_unit_t<128><<<grid, dim3(256), 0, stream>>>(pos, dist, out);
    } else {
        const long long total = (long long)B * N * N * N;
        int blocks = (int)((total + 255) / 256);
        if (blocks > 131072) blocks = 131072;
        if (blocks < 1) blocks = 1;
        angle_scalar<<<blocks, dim3(256), 0, stream>>>(pos, dist, out, N, total);
    }
}